// Round 11
// baseline (23482.581 us; speedup 1.0000x reference)
//
#include <hip/hip_runtime.h>

// ---------------------------------------------------------------------------
// Encoder: B=64, T=2048, D=256, U=256, UEP=64
//  Phase 1a: s1  = ln(x @ W + b)    -> f16   [131072][768]
//  Phase 1b: s1e = ln(x @ W_EP + b) -> f64   [131072][192]  (exact fp64)
//  Phase 2 (R11): 64 WGs x 256 thr (4 waves), 4 raw barriers/step.
//    Empirical law from R1/R2/R3: step-time ~ 0.18us x barriers x waves + 1.7us
//    -> halving waves 8->4 should cut ~1.4us/step. VGPR cap observation
//    (VGPR_Count == 65536/threads) says 256 thr allows 256 VGPRs.
//    Thread t owns z-col t AND r-col 256+t (one h-broadcast read serves both).
//    Uzr streamed per step from L2, chunk-major coalesced, depth-3 pipeline,
//    LICM defeated via asm-obscured base pointer. Uh LDS-resident.
//    EP GRU + is_end: fp64 (discrete round(sigmoid) must match reference).
// ---------------------------------------------------------------------------

typedef _Float16 h2  __attribute__((ext_vector_type(2)));
typedef _Float16 v8h __attribute__((ext_vector_type(8)));

__device__ __forceinline__ float fdot2_(h2 a, h2 b, float c) {
#if __has_builtin(__builtin_amdgcn_fdot2)
  return __builtin_amdgcn_fdot2(a, b, c, false);
#else
  return c + (float)a[0] * (float)b[0] + (float)a[1] * (float)b[1];
#endif
}

template <int I>
__device__ __forceinline__ h2 pr(v8h v) {
  h2 r; r[0] = v[2 * I]; r[1] = v[2 * I + 1]; return r;
}

// Raw barrier: order LDS (lgkmcnt) but leave global loads/stores in flight.
__device__ __forceinline__ void wg_barrier() {
  __builtin_amdgcn_sched_barrier(0);
  asm volatile("s_waitcnt lgkmcnt(0)" ::: "memory");
  __builtin_amdgcn_sched_barrier(0);
  __builtin_amdgcn_s_barrier();
  __builtin_amdgcn_sched_barrier(0);
}

// block K: chunks 4K..4K+3 of z-col tz and r-col tr (uzr chunk-major [c][512][8])
template <int K>
__device__ __forceinline__ void ldblk(v8h* d, const v8h* base, int tz, int tr) {
  #pragma unroll
  for (int i = 0; i < 4; ++i) {
    d[i]     = base[(size_t)(4 * K + i) * 512 + tz];
    d[4 + i] = base[(size_t)(4 * K + i) * 512 + tr];
  }
}
template <int K>
__device__ __forceinline__ void dotblk(const v8h* hv, const v8h* d,
    float& za0, float& za1, float& za2, float& za3,
    float& ra0, float& ra1, float& ra2, float& ra3) {
  #pragma unroll
  for (int i = 0; i < 4; ++i) {
    const v8h hc = hv[4 * K + i];
    za0 = fdot2_(pr<0>(hc), pr<0>(d[i]), za0);
    za1 = fdot2_(pr<1>(hc), pr<1>(d[i]), za1);
    za2 = fdot2_(pr<2>(hc), pr<2>(d[i]), za2);
    za3 = fdot2_(pr<3>(hc), pr<3>(d[i]), za3);
    ra0 = fdot2_(pr<0>(hc), pr<0>(d[4 + i]), ra0);
    ra1 = fdot2_(pr<1>(hc), pr<1>(d[4 + i]), ra1);
    ra2 = fdot2_(pr<2>(hc), pr<2>(d[4 + i]), ra2);
    ra3 = fdot2_(pr<3>(hc), pr<3>(d[4 + i]), ra3);
  }
}

// ---------------------------------------------------------------------------
// prep: wt j-major (R6-proven), uzr CHUNK-MAJOR [c][512][8], uh chunk pages,
// wept transpose.
// ---------------------------------------------------------------------------
__global__ __launch_bounds__(256) void prep_kernel(
    const float* __restrict__ W, const float* __restrict__ U,
    const float* __restrict__ W_EP,
    _Float16* __restrict__ wt, _Float16* __restrict__ uzr,
    _Float16* __restrict__ uh, float* __restrict__ wept)
{
  const int blk = blockIdx.x;
  const int k = threadIdx.x;
  if (blk < 768) {                       // wt[j][k] = W[k][j]  (f16)
    const int j = blk;
    wt[(size_t)j * 256 + k] = (_Float16)W[(size_t)k * 768 + j];
  } else if (blk < 1280) {               // uzr[c][j][e] = U[8c+e][j], j<512
    const int j = blk - 768;
    const int c = k >> 3, e = k & 7;
    uzr[((size_t)c * 512 + j) * 8 + e] = (_Float16)U[(size_t)k * 768 + j];
  } else if (blk < 1536) {               // uh chunk pages [p][256][8]
    const int j = blk - 1280;
    const int p = k >> 3, e = k & 7;
    uh[((size_t)p * 256 + j) * 8 + e] = (_Float16)U[(size_t)k * 768 + 512 + j];
  } else {                               // wept[j][k] = W_EP[k][j] (f32)
    const int j = blk - 1536;
    wept[(size_t)j * 256 + k] = W_EP[(size_t)k * 192 + j];
  }
}

// ---------------------------------------------------------------------------
// Phase 1a: main s1 = ln(x@W + b, gammas[0], betas[0]) stored f16. (R6-proven)
// ---------------------------------------------------------------------------
__global__ __launch_bounds__(256) void ph1_main_kernel(
    const float* __restrict__ x, const _Float16* __restrict__ wt,
    const float* __restrict__ bvec, const float* __restrict__ gam,
    const float* __restrict__ bet, _Float16* __restrict__ s1out)
{
  __shared__ __align__(16) _Float16 xs[16][256];
  __shared__ float sp[16][768];
  const int tid = threadIdx.x;
  const size_t row0 = (size_t)blockIdx.x * 16;

  #pragma unroll
  for (int i = 0; i < 16; ++i)
    xs[i][tid] = (_Float16)x[(row0 + i) * 256 + tid];
  __syncthreads();

  #pragma unroll 1
  for (int cc = 0; cc < 3; ++cc) {
    const int col = cc * 256 + tid;
    const v8h* wp = (const v8h*)(wt + (size_t)col * 256);
    float acc[16];
    #pragma unroll
    for (int r = 0; r < 16; ++r) acc[r] = 0.f;
    #pragma unroll 4
    for (int c = 0; c < 32; ++c) {
      const v8h w8 = wp[c];
      #pragma unroll
      for (int r = 0; r < 16; ++r) {
        const v8h x8 = *(const v8h*)(&xs[r][c * 8]);
        acc[r] = fdot2_(pr<0>(x8), pr<0>(w8), acc[r]);
        acc[r] = fdot2_(pr<1>(x8), pr<1>(w8), acc[r]);
        acc[r] = fdot2_(pr<2>(x8), pr<2>(w8), acc[r]);
        acc[r] = fdot2_(pr<3>(x8), pr<3>(w8), acc[r]);
      }
    }
    const float bb = bvec[col];
    #pragma unroll
    for (int r = 0; r < 16; ++r) sp[r][col] = acc[r] + bb;
  }
  __syncthreads();

  const int w = tid >> 6, lane = tid & 63;
  for (int rr = 0; rr < 4; ++rr) {
    const int r = (w << 2) | rr;
    float vals[12], sum = 0.f, sq = 0.f;
    #pragma unroll
    for (int j = 0; j < 12; ++j) {
      const float v = sp[r][lane + (j << 6)];
      vals[j] = v; sum += v; sq += v * v;
    }
    #pragma unroll
    for (int m = 32; m >= 1; m >>= 1) {
      sum += __shfl_xor(sum, m); sq += __shfl_xor(sq, m);
    }
    const float mean = sum * (1.f / 768.f);
    const float var = sq * (1.f / 768.f) - mean * mean;
    const float inv = 1.f / (sqrtf(var + 1e-5f) + 1e-5f);
    #pragma unroll
    for (int j = 0; j < 12; ++j) {
      const int c = lane + (j << 6);
      s1out[(row0 + r) * 768 + c] =
          (_Float16)(gam[c] * ((vals[j] - mean) * inv) + bet[c]);
    }
  }
}

// ---------------------------------------------------------------------------
// Phase 1b: EP s1e = ln(x@W_EP + b_EP) in exact fp64. (R6-proven)
// ---------------------------------------------------------------------------
__global__ __launch_bounds__(192) void ph1_ep_kernel(
    const float* __restrict__ x, const float* __restrict__ wept,
    const float* __restrict__ bvec, const float* __restrict__ gam,
    const float* __restrict__ bet, void* __restrict__ s1e, const int store64)
{
  __shared__ __align__(16) float xs[16][256];
  __shared__ double sp[16][192];
  const int tid = threadIdx.x;
  const size_t row0 = (size_t)blockIdx.x * 16;

  for (int idx = tid; idx < 4096; idx += 192)
    xs[idx >> 8][idx & 255] = x[row0 * 256 + idx];
  __syncthreads();

  {
    const float4* wp = (const float4*)(wept + (size_t)tid * 256);
    double acc[16];
    #pragma unroll
    for (int r = 0; r < 16; ++r) acc[r] = 0.0;
    #pragma unroll 2
    for (int c = 0; c < 64; ++c) {
      const float4 w4 = wp[c];
      #pragma unroll
      for (int r = 0; r < 16; ++r) {
        const float4 x4 = *(const float4*)(&xs[r][c * 4]);
        acc[r] += (double)x4.x * (double)w4.x;
        acc[r] += (double)x4.y * (double)w4.y;
        acc[r] += (double)x4.z * (double)w4.z;
        acc[r] += (double)x4.w * (double)w4.w;
      }
    }
    const double bb = (double)bvec[tid];
    #pragma unroll
    for (int r = 0; r < 16; ++r) sp[r][tid] = acc[r] + bb;
  }
  __syncthreads();

  const int w = tid >> 6, lane = tid & 63;
  for (int r = w; r < 16; r += 3) {
    double vals[3], sum = 0.0, sq = 0.0;
    #pragma unroll
    for (int j = 0; j < 3; ++j) {
      const double v = sp[r][lane + (j << 6)];
      vals[j] = v; sum += v; sq += v * v;
    }
    #pragma unroll
    for (int m = 32; m >= 1; m >>= 1) {
      sum += __shfl_xor(sum, m); sq += __shfl_xor(sq, m);
    }
    const double mean = sum * (1.0 / 192.0);
    const double var = sq * (1.0 / 192.0) - mean * mean;
    const double den = sqrt(var + 1e-5) + 1e-5;
    #pragma unroll
    for (int j = 0; j < 3; ++j) {
      const int c = lane + (j << 6);
      const double vv = (double)gam[c] * ((vals[j] - mean) / den) + (double)bet[c];
      if (store64) ((double*)s1e)[(row0 + r) * 192 + c] = vv;
      else         ((float*)s1e)[(row0 + r) * 192 + c] = (float)vv;
    }
  }
}

// ---------------------------------------------------------------------------
// Phase 2 LDS map (dynamic, 144192 B) — same footprint as R6
// ---------------------------------------------------------------------------
#define OFF_UH     0        /* 131072  f16 Uh chunk pages [32][256][8]      */
#define OFF_MASK   131072   /* 8192    int mask row                          */
#define OFF_HEP    139264   /* 512     f64 hep[64]                           */
#define OFF_ZEE    139776   /* 512     f64 ze[64]                            */
#define OFF_RHEP   140288   /* 512     f64 rhep[64]                          */
#define OFF_EPZRP  140800   /* 64      double2 epzrP[4]                      */
#define OFF_EPHHP  140928   /* 64      double2 ephhP[4]                      */
#define OFF_H2     140992   /* 512     f16 h packed h2[128]                  */
#define OFF_RH     141504   /* 512     f16 rh packed                         */
#define OFF_HF     142016   /* 1024    f32 h[256]                            */
#define OFF_ZRP    144064   /* 32      float2 zrP[4]                         */
#define OFF_HHP    144128   /* 32      float2 hhP[4]                         */
#define OFF_FLAG   144160   /* 8       f32 flag[2]                           */
#define SCAN_LDS_BYTES 144192

__global__ __launch_bounds__(256, 1) void scan_kernel(
    const _Float16* __restrict__ uzr_g, const _Float16* __restrict__ uh_g,
    const float* __restrict__ U_EP, const _Float16* __restrict__ s1,
    const void* __restrict__ s1e_v, const int s1e64,
    const int* __restrict__ mask,
    const float* __restrict__ gam1, const float* __restrict__ bet1,
    const float* __restrict__ gamep1, const float* __restrict__ betep1,
    const float* __restrict__ W1, const float* __restrict__ b1,
    float* __restrict__ out)
{
  extern __shared__ char sm[];
  const int t = threadIdx.x;            // 0..255
  const int b = blockIdx.x;
  const int w = t >> 6;                 // wave 0..3
  const int lane = t & 63;
  const int qe  = t & 3;                // EP K-slice (rows 16qe..16qe+15)
  const int je  = t >> 2;               // EP col 0..63 (pass A); pass B = 64+je

  float*  hf    = (float*)(sm + OFF_HF);
  float*  flagp = (float*)(sm + OFF_FLAG);
  double* hepd  = (double*)(sm + OFF_HEP);
  int*    maskl = (int*)(sm + OFF_MASK);

  // ---- stage Uh ----
  {
    const v8h* src = (const v8h*)uh_g;
    v8h* dst = (v8h*)(sm + OFF_UH);
    #pragma unroll
    for (int i = 0; i < 32; ++i) dst[i * 256 + t] = src[i * 256 + t];
  }
  // ---- stage mask row ----
  #pragma unroll
  for (int i = 0; i < 8; ++i) maskl[i * 256 + t] = mask[((size_t)b << 11) + i * 256 + t];

  // ---- EP weights (f32 regs): pass A col je, pass B col 64+je, hh col je ----
  float uezA[16], uezB[16], ueh[16];
  #pragma unroll
  for (int i = 0; i < 16; ++i) uezA[i] = U_EP[(size_t)(16 * qe + i) * 192 + je];
  #pragma unroll
  for (int i = 0; i < 16; ++i) uezB[i] = U_EP[(size_t)(16 * qe + i) * 192 + 64 + je];
  #pragma unroll
  for (int i = 0; i < 16; ++i) ueh[i] = U_EP[(size_t)(16 * qe + i) * 192 + 128 + je];

  // ---- constants ----
  const float gz  = gam1[t],        bz  = bet1[t];          // z col t
  const float gzr = gam1[256 + t],  bzr = bet1[256 + t];    // r col 256+t
  const float gh  = gam1[512 + t],  bh  = bet1[512 + t];    // hh col t
  const float gseA = gamep1[je],       bseA = betep1[je];
  const float gseB = gamep1[64 + je],  bseB = betep1[64 + je];
  const float ghe  = gamep1[128 + je], bhe  = betep1[128 + je];
  const double w1d = (double)W1[lane];
  const double b1d = (double)b1[0];
  const double* dptr = (const double*)s1e_v;
  const float*  fptr = (const float*)s1e_v;

  // ---- init state ----
  if (t < 128) { h2 z2; z2[0] = (_Float16)0.f; z2[1] = (_Float16)0.f;
                 ((h2*)(sm + OFF_H2))[t] = z2; }
  hf[t] = 0.f;
  if (t < 64)  hepd[t] = 0.0;
  if (t < 2)   flagp[t] = 0.f;

  // ---- prefetch step 0 ----
  const size_t n0 = (size_t)b << 11;
  float  s1zA_c = (float)s1[n0 * 768 + t];
  float  s1zB_c = (float)s1[n0 * 768 + 256 + t];
  float  s1h_c  = (float)s1[n0 * 768 + 512 + t];
  double s1eA_c = s1e64 ? dptr[n0 * 192 + je]      : (double)fptr[n0 * 192 + je];
  double s1eB_c = s1e64 ? dptr[n0 * 192 + 64 + je] : (double)fptr[n0 * 192 + 64 + je];
  double s1eh_c = s1e64 ? dptr[n0 * 192 + 128 + je]: (double)fptr[n0 * 192 + 128 + je];
  __syncthreads();

  for (int tt = 0; tt < 2048; ++tt) {
    const size_t n = ((size_t)b << 11) | (size_t)tt;
    const float fz = (flagp[tt & 1] > 0.5f) ? 0.f : 1.f;

    // ---- Seg1: deferred h-write | prefetch t+1 | Uzr stream+dots | EP-zr | is_end
    if (tt > 0) out[(n - 1) * 256 + t] = hf[t];

    const int ttn = (tt < 2047) ? tt + 1 : 2047;
    const size_t np1 = ((size_t)b << 11) | (size_t)ttn;
    const float  s1zA_n = (float)s1[np1 * 768 + t];
    const float  s1zB_n = (float)s1[np1 * 768 + 256 + t];
    const float  s1h_n  = (float)s1[np1 * 768 + 512 + t];
    const double s1eA_n = s1e64 ? dptr[np1 * 192 + je]       : (double)fptr[np1 * 192 + je];
    const double s1eB_n = s1e64 ? dptr[np1 * 192 + 64 + je]  : (double)fptr[np1 * 192 + 64 + je];
    const double s1eh_n = s1e64 ? dptr[np1 * 192 + 128 + je] : (double)fptr[np1 * 192 + 128 + je];

    // Uzr stream: depth-3 ping-pong, chunk-major coalesced, LICM-defeated
    const v8h* uzb = (const v8h*)uzr_g;
    asm volatile("" : "+v"(uzb));
    v8h A[8], Bv[8], Cv[8];
    ldblk<0>(A, uzb, t, 256 + t);
    ldblk<1>(Bv, uzb, t, 256 + t);
    ldblk<2>(Cv, uzb, t, 256 + t);

    const v8h* hv = (const v8h*)(sm + OFF_H2);
    float za0 = 0.f, za1 = 0.f, za2 = 0.f, za3 = 0.f;
    float ra0 = 0.f, ra1 = 0.f, ra2 = 0.f, ra3 = 0.f;
    dotblk<0>(hv, A,  za0, za1, za2, za3, ra0, ra1, ra2, ra3);
    ldblk<3>(A, uzb, t, 256 + t);
    dotblk<1>(hv, Bv, za0, za1, za2, za3, ra0, ra1, ra2, ra3);
    ldblk<4>(Bv, uzb, t, 256 + t);
    dotblk<2>(hv, Cv, za0, za1, za2, za3, ra0, ra1, ra2, ra3);
    ldblk<5>(Cv, uzb, t, 256 + t);
    dotblk<3>(hv, A,  za0, za1, za2, za3, ra0, ra1, ra2, ra3);
    ldblk<6>(A, uzb, t, 256 + t);
    dotblk<4>(hv, Bv, za0, za1, za2, za3, ra0, ra1, ra2, ra3);
    ldblk<7>(Bv, uzb, t, 256 + t);

    // EP-zr (fp64), 2 passes — covers tail load latency
    double deA, deB;
    {
      const double2* hp = (const double2*)(hepd + 16 * qe);
      double accA = 0.0, accB = 0.0;
      #pragma unroll
      for (int i = 0; i < 8; ++i) {
        const double2 hv2 = hp[i];
        accA += hv2.x * (double)uezA[2 * i] + hv2.y * (double)uezA[2 * i + 1];
        accB += hv2.x * (double)uezB[2 * i] + hv2.y * (double)uezB[2 * i + 1];
      }
      accA += __shfl_xor(accA, 1); accA += __shfl_xor(accA, 2);
      accB += __shfl_xor(accB, 1); accB += __shfl_xor(accB, 2);
      deA = accA; deB = accB;
      double es = deA + deB, eq = deA * deA + deB * deB;
      #pragma unroll
      for (int m = 4; m <= 32; m <<= 1) { es += __shfl_xor(es, m); eq += __shfl_xor(eq, m); }
      if (lane == 0) ((double2*)(sm + OFF_EPZRP))[w] = make_double2(es, eq);
    }
    if (w == 3) {                       // is_end from hep (pre-update)
      double p = hepd[lane] * w1d;
      #pragma unroll
      for (int m = 1; m <= 32; m <<= 1) p += __shfl_xor(p, m);
      if (t == 192) {
        const float e = ((p + b1d) > 0.0) ? 1.f : 0.f;
        flagp[(tt + 1) & 1] = e;
        out[(size_t)33554432 + n] = e;
      }
    }

    dotblk<5>(hv, Cv, za0, za1, za2, za3, ra0, ra1, ra2, ra3);
    dotblk<6>(hv, A,  za0, za1, za2, za3, ra0, ra1, ra2, ra3);
    dotblk<7>(hv, Bv, za0, za1, za2, za3, ra0, ra1, ra2, ra3);
    const float dz = ((za0 + za1) + (za2 + za3)) * fz;
    const float dr = ((ra0 + ra1) + (ra2 + ra3)) * fz;
    {
      float s_ = dz + dr, q_ = dz * dz + dr * dr;
      #pragma unroll
      for (int m = 1; m <= 32; m <<= 1) { s_ += __shfl_xor(s_, m); q_ += __shfl_xor(q_, m); }
      if (lane == 0) ((float2*)(sm + OFF_ZRP))[w] = make_float2(s_, q_);
    }
    wg_barrier();  // B1

    // ---- Seg2: LN512 -> z(reg) / rh | EP LN128 -> ze / rhep ----
    float zreg;
    {
      float S = 0.f, Q = 0.f;
      const float4* zp = (const float4*)(sm + OFF_ZRP);
      #pragma unroll
      for (int i = 0; i < 2; ++i) { const float4 v = zp[i]; S += v.x + v.z; Q += v.y + v.w; }
      const float mean = S * (1.f / 512.f);
      const float var = Q * (1.f / 512.f) - mean * mean;
      const float inv = 1.f / (sqrtf(var + 1e-5f) + 1e-5f);
      float sz = 0.2f * (s1zA_c + (gz * ((dz - mean) * inv) + bz)) + 0.5f;
      zreg = fminf(fmaxf(sz, 0.f), 1.f);
      float sr = 0.2f * (s1zB_c + (gzr * ((dr - mean) * inv) + bzr)) + 0.5f;
      sr = fminf(fmaxf(sr, 0.f), 1.f);
      ((_Float16*)(sm + OFF_RH))[t] = (_Float16)(sr * (fz * hf[t]));
    }
    if (qe == 0) {                      // EP-zr finish (64 threads, cols je & 64+je)
      double S = 0.0, Q = 0.0;
      const double2* ep = (const double2*)(sm + OFF_EPZRP);
      #pragma unroll
      for (int i = 0; i < 4; ++i) { S += ep[i].x; Q += ep[i].y; }
      const double mean = S * (1.0 / 128.0);
      const double var = Q * (1.0 / 128.0) - mean * mean;
      const double den = sqrt(var + 1e-5) + 1e-5;
      double seA = 0.2 * (s1eA_c + ((double)gseA * ((deA - mean) / den) + (double)bseA)) + 0.5;
      seA = fmin(fmax(seA, 0.0), 1.0);
      ((double*)(sm + OFF_ZEE))[je] = seA;
      double seB = 0.2 * (s1eB_c + ((double)gseB * ((deB - mean) / den) + (double)bseB)) + 0.5;
      seB = fmin(fmax(seB, 0.0), 1.0);
      ((double*)(sm + OFF_RHEP))[je] = seB * hepd[je];
    }
    wg_barrier();  // B2

    // ---- Seg3: hh dot (col t, Uh pages + rh broadcast) | EP-hh dot ----
    float dh;
    {
      const v8h* rhv8 = (const v8h*)(sm + OFF_RH);
      const v8h* uhv  = (const v8h*)(sm + OFF_UH);
      float c0 = 0.f, c1 = 0.f, c2 = 0.f, c3 = 0.f;
      #pragma unroll
      for (int p = 0; p < 32; ++p) {
        const v8h rc = rhv8[p];
        const v8h uc = uhv[p * 256 + t];
        c0 = fdot2_(pr<0>(rc), pr<0>(uc), c0);
        c1 = fdot2_(pr<1>(rc), pr<1>(uc), c1);
        c2 = fdot2_(pr<2>(rc), pr<2>(uc), c2);
        c3 = fdot2_(pr<3>(rc), pr<3>(uc), c3);
      }
      dh = (c0 + c1) + (c2 + c3);
      float s_ = dh, q_ = dh * dh;
      #pragma unroll
      for (int m = 1; m <= 32; m <<= 1) { s_ += __shfl_xor(s_, m); q_ += __shfl_xor(q_, m); }
      if (lane == 0) ((float2*)(sm + OFF_HHP))[w] = make_float2(s_, q_);
    }
    double deh;
    {
      const double2* rp = (const double2*)((double*)(sm + OFF_RHEP) + 16 * qe);
      double acc = 0.0;
      #pragma unroll
      for (int i = 0; i < 8; ++i) {
        const double2 rv = rp[i];
        acc += rv.x * (double)ueh[2 * i] + rv.y * (double)ueh[2 * i + 1];
      }
      acc += __shfl_xor(acc, 1); acc += __shfl_xor(acc, 2);
      deh = acc;
      double es = deh, eq = deh * deh;
      #pragma unroll
      for (int m = 4; m <= 32; m <<= 1) { es += __shfl_xor(es, m); eq += __shfl_xor(eq, m); }
      if (lane == 0) ((double2*)(sm + OFF_EPHHP))[w] = make_double2(es, eq);
    }
    wg_barrier();  // B3

    // ---- Seg4: main h update | EP hep update ----
    const int xm = maskl[tt];
    {
      float S = 0.f, Q = 0.f;
      const float4* hp4 = (const float4*)(sm + OFF_HHP);
      #pragma unroll
      for (int i = 0; i < 2; ++i) { const float4 v = hp4[i]; S += v.x + v.z; Q += v.y + v.w; }
      const float mean = S * (1.f / 256.f);
      const float var = Q * (1.f / 256.f) - mean * mean;
      const float inv = 1.f / (sqrtf(var + 1e-5f) + 1e-5f);
      const float hhv = gh * ((dh - mean) * inv) + bh;
      const float hzf = fz * hf[t];
      const float hn = zreg * hzf + (1.f - zreg) * tanhf(s1h_c + hhv);
      const float hc_ = (xm > 0) ? hn : hzf;
      hf[t] = hc_;
      const float ho = __shfl_xor(hc_, 1);
      if (!(t & 1)) {
        h2 p2; p2[0] = (_Float16)hc_; p2[1] = (_Float16)ho;
        ((h2*)(sm + OFF_H2))[t >> 1] = p2;
      }
    }
    if (qe == 0) {                      // EP finish (64 threads, col je)
      double S = 0.0, Q = 0.0;
      const double2* ep = (const double2*)(sm + OFF_EPHHP);
      #pragma unroll
      for (int i = 0; i < 4; ++i) { S += ep[i].x; Q += ep[i].y; }
      const double mean = S * (1.0 / 64.0);
      const double var = Q * (1.0 / 64.0) - mean * mean;
      const double den = sqrt(var + 1e-5) + 1e-5;
      const double hhe = (double)ghe * ((deh - mean) / den) + (double)bhe;
      const double ze = ((double*)(sm + OFF_ZEE))[je];
      const double hold = hepd[je];
      const double hepn = ze * hold + (1.0 - ze) * tanh(s1eh_c + hhe);
      hepd[je] = (xm > 0) ? hepn : hold;
    }
    wg_barrier();  // B4

    s1zA_c = s1zA_n; s1zB_c = s1zB_n; s1h_c = s1h_n;
    s1eA_c = s1eA_n; s1eB_c = s1eB_n; s1eh_c = s1eh_n;
  }
  // final h write (step 2047)
  out[((((size_t)b << 11) | 2047)) * 256 + t] = hf[t];
}

// ---------------------------------------------------------------------------
extern "C" void kernel_launch(void* const* d_in, const int* in_sizes, int n_in,
                              void* d_out, int out_size, void* d_ws, size_t ws_size,
                              hipStream_t stream)
{
  (void)in_sizes; (void)n_in; (void)out_size;
  const float* x       = (const float*)d_in[0];
  const int*   mask    = (const int*)d_in[1];
  const float* W       = (const float*)d_in[2];
  const float* U       = (const float*)d_in[3];
  const float* bvec    = (const float*)d_in[4];
  const float* gammas  = (const float*)d_in[5];
  const float* betas   = (const float*)d_in[6];
  const float* W_EP    = (const float*)d_in[7];
  const float* U_EP    = (const float*)d_in[8];
  const float* b_EP    = (const float*)d_in[9];
  const float* gammasE = (const float*)d_in[10];
  const float* betasE  = (const float*)d_in[11];
  const float* W1_EP   = (const float*)d_in[12];
  const float* b1_EP   = (const float*)d_in[13];
  float* out = (float*)d_out;

  const size_t NR = 131072;                 // B*T
  const size_t S1_SZ    = NR * 768 * 2;     // f16
  const size_t S1E64_SZ = NR * 192 * 8;     // f64
  const size_t S1E32_SZ = NR * 192 * 4;     // f32 fallback
  const size_t WSMALL = 262144 + 131072 + 393216 + 196608;
  const int s1e64 = (ws_size >= S1_SZ + S1E64_SZ + WSMALL) ? 1 : 0;
  const size_t S1E_SZ = s1e64 ? S1E64_SZ : S1E32_SZ;
  if (ws_size < S1_SZ + S1E32_SZ + WSMALL) return;  // cannot run

  char* ws = (char*)d_ws;
  size_t off = 0;
  void* s1e      = (void*)(ws + off);      off += S1E_SZ;
  _Float16* s1   = (_Float16*)(ws + off);  off += S1_SZ;
  _Float16* uzr  = (_Float16*)(ws + off);  off += 262144;
  _Float16* uh   = (_Float16*)(ws + off);  off += 131072;
  _Float16* wt   = (_Float16*)(ws + off);  off += 393216;
  float* wept    = (float*)(ws + off);     off += 196608;

  prep_kernel<<<dim3(1728), dim3(256), 0, stream>>>(
      W, U, W_EP, wt, uzr, uh, wept);
  ph1_main_kernel<<<dim3(8192), dim3(256), 0, stream>>>(
      x, wt, bvec, gammas, betas, s1);
  ph1_ep_kernel<<<dim3(8192), dim3(192), 0, stream>>>(
      x, wept, b_EP, gammasE, betasE, s1e, s1e64);

  hipFuncSetAttribute(reinterpret_cast<const void*>(scan_kernel),
                      hipFuncAttributeMaxDynamicSharedMemorySize, SCAN_LDS_BYTES);
  scan_kernel<<<dim3(64), dim3(256), SCAN_LDS_BYTES, stream>>>(
      uzr, uh, U_EP, s1, (const void*)s1e, s1e64, mask,
      gammas + 768, betas + 768, gammasE + 192, betasE + 192,
      W1_EP, b1_EP, out);
}

// Round 12
// 18938.037 us; speedup vs baseline: 1.2400x; 1.2400x over previous
//
#include <hip/hip_runtime.h>

// ---------------------------------------------------------------------------
// Encoder: B=64, T=2048, D=256, U=256, UEP=64
//  Phase 1a: s1  = ln(x @ W + b)    -> f16   [131072][768]
//  Phase 1b: s1e = ln(x @ W_EP + b) -> f64   [131072][192]  (exact fp64)
//  Phase 2 (R12): R6 structure (64 WGs x 512 thr, 8 waves, 4 raw barriers)
//    with the zr-weight access rebuilt as an explicit depth-2 pipelined,
//    coalesced chunk-major L2 stream (32x dwordx4/thread/step, 8KB in
//    flight per wave). R11 proved the 65536-word/WG VGPR cap: at 512 thr
//    weights can never be register-resident, so R3-R10's 7.5us/step was
//    spill-reload serialization. 8 waves x pipelined stream saturates the
//    per-CU L2 port instead (~1.8us/step floor).
//    EP GRU + is_end stay fused (they overlap for free, R6-proven).
// ---------------------------------------------------------------------------

typedef _Float16 h2  __attribute__((ext_vector_type(2)));
typedef _Float16 v8h __attribute__((ext_vector_type(8)));

__device__ __forceinline__ float fdot2_(h2 a, h2 b, float c) {
#if __has_builtin(__builtin_amdgcn_fdot2)
  return __builtin_amdgcn_fdot2(a, b, c, false);
#else
  return c + (float)a[0] * (float)b[0] + (float)a[1] * (float)b[1];
#endif
}

template <int I>
__device__ __forceinline__ h2 pr(v8h v) {
  h2 r; r[0] = v[2 * I]; r[1] = v[2 * I + 1]; return r;
}

// Raw barrier: order LDS (lgkmcnt) but leave global loads/stores in flight.
__device__ __forceinline__ void wg_barrier() {
  __builtin_amdgcn_sched_barrier(0);
  asm volatile("s_waitcnt lgkmcnt(0)" ::: "memory");
  __builtin_amdgcn_sched_barrier(0);
  __builtin_amdgcn_s_barrier();
  __builtin_amdgcn_sched_barrier(0);
}

// ---------------------------------------------------------------------------
// prep: wt j-major (R6-proven), uzr CHUNK-MAJOR [c][512][8] (R11-proven),
// uh chunk pages, wept transpose.
// ---------------------------------------------------------------------------
__global__ __launch_bounds__(256) void prep_kernel(
    const float* __restrict__ W, const float* __restrict__ U,
    const float* __restrict__ W_EP,
    _Float16* __restrict__ wt, _Float16* __restrict__ uzr,
    _Float16* __restrict__ uh, float* __restrict__ wept)
{
  const int blk = blockIdx.x;
  const int k = threadIdx.x;
  if (blk < 768) {                       // wt[j][k] = W[k][j]  (f16)
    const int j = blk;
    wt[(size_t)j * 256 + k] = (_Float16)W[(size_t)k * 768 + j];
  } else if (blk < 1280) {               // uzr[c][j][e] = U[8c+e][j], j<512
    const int j = blk - 768;
    const int c = k >> 3, e = k & 7;
    uzr[((size_t)c * 512 + j) * 8 + e] = (_Float16)U[(size_t)k * 768 + j];
  } else if (blk < 1536) {               // uh chunk pages [p][256][8]
    const int j = blk - 1280;
    const int p = k >> 3, e = k & 7;
    uh[((size_t)p * 256 + j) * 8 + e] = (_Float16)U[(size_t)k * 768 + 512 + j];
  } else {                               // wept[j][k] = W_EP[k][j] (f32)
    const int j = blk - 1536;
    wept[(size_t)j * 256 + k] = W_EP[(size_t)k * 192 + j];
  }
}

// ---------------------------------------------------------------------------
// Phase 1a: main s1 = ln(x@W + b, gammas[0], betas[0]) stored f16. (R6-proven)
// ---------------------------------------------------------------------------
__global__ __launch_bounds__(256) void ph1_main_kernel(
    const float* __restrict__ x, const _Float16* __restrict__ wt,
    const float* __restrict__ bvec, const float* __restrict__ gam,
    const float* __restrict__ bet, _Float16* __restrict__ s1out)
{
  __shared__ __align__(16) _Float16 xs[16][256];
  __shared__ float sp[16][768];
  const int tid = threadIdx.x;
  const size_t row0 = (size_t)blockIdx.x * 16;

  #pragma unroll
  for (int i = 0; i < 16; ++i)
    xs[i][tid] = (_Float16)x[(row0 + i) * 256 + tid];
  __syncthreads();

  #pragma unroll 1
  for (int cc = 0; cc < 3; ++cc) {
    const int col = cc * 256 + tid;
    const v8h* wp = (const v8h*)(wt + (size_t)col * 256);
    float acc[16];
    #pragma unroll
    for (int r = 0; r < 16; ++r) acc[r] = 0.f;
    #pragma unroll 4
    for (int c = 0; c < 32; ++c) {
      const v8h w8 = wp[c];
      #pragma unroll
      for (int r = 0; r < 16; ++r) {
        const v8h x8 = *(const v8h*)(&xs[r][c * 8]);
        acc[r] = fdot2_(pr<0>(x8), pr<0>(w8), acc[r]);
        acc[r] = fdot2_(pr<1>(x8), pr<1>(w8), acc[r]);
        acc[r] = fdot2_(pr<2>(x8), pr<2>(w8), acc[r]);
        acc[r] = fdot2_(pr<3>(x8), pr<3>(w8), acc[r]);
      }
    }
    const float bb = bvec[col];
    #pragma unroll
    for (int r = 0; r < 16; ++r) sp[r][col] = acc[r] + bb;
  }
  __syncthreads();

  const int w = tid >> 6, lane = tid & 63;
  for (int rr = 0; rr < 4; ++rr) {
    const int r = (w << 2) | rr;
    float vals[12], sum = 0.f, sq = 0.f;
    #pragma unroll
    for (int j = 0; j < 12; ++j) {
      const float v = sp[r][lane + (j << 6)];
      vals[j] = v; sum += v; sq += v * v;
    }
    #pragma unroll
    for (int m = 32; m >= 1; m >>= 1) {
      sum += __shfl_xor(sum, m); sq += __shfl_xor(sq, m);
    }
    const float mean = sum * (1.f / 768.f);
    const float var = sq * (1.f / 768.f) - mean * mean;
    const float inv = 1.f / (sqrtf(var + 1e-5f) + 1e-5f);
    #pragma unroll
    for (int j = 0; j < 12; ++j) {
      const int c = lane + (j << 6);
      s1out[(row0 + r) * 768 + c] =
          (_Float16)(gam[c] * ((vals[j] - mean) * inv) + bet[c]);
    }
  }
}

// ---------------------------------------------------------------------------
// Phase 1b: EP s1e = ln(x@W_EP + b_EP) in exact fp64. (R6-proven)
// ---------------------------------------------------------------------------
__global__ __launch_bounds__(192) void ph1_ep_kernel(
    const float* __restrict__ x, const float* __restrict__ wept,
    const float* __restrict__ bvec, const float* __restrict__ gam,
    const float* __restrict__ bet, void* __restrict__ s1e, const int store64)
{
  __shared__ __align__(16) float xs[16][256];
  __shared__ double sp[16][192];
  const int tid = threadIdx.x;
  const size_t row0 = (size_t)blockIdx.x * 16;

  for (int idx = tid; idx < 4096; idx += 192)
    xs[idx >> 8][idx & 255] = x[row0 * 256 + idx];
  __syncthreads();

  {
    const float4* wp = (const float4*)(wept + (size_t)tid * 256);
    double acc[16];
    #pragma unroll
    for (int r = 0; r < 16; ++r) acc[r] = 0.0;
    #pragma unroll 2
    for (int c = 0; c < 64; ++c) {
      const float4 w4 = wp[c];
      #pragma unroll
      for (int r = 0; r < 16; ++r) {
        const float4 x4 = *(const float4*)(&xs[r][c * 4]);
        acc[r] += (double)x4.x * (double)w4.x;
        acc[r] += (double)x4.y * (double)w4.y;
        acc[r] += (double)x4.z * (double)w4.z;
        acc[r] += (double)x4.w * (double)w4.w;
      }
    }
    const double bb = (double)bvec[tid];
    #pragma unroll
    for (int r = 0; r < 16; ++r) sp[r][tid] = acc[r] + bb;
  }
  __syncthreads();

  const int w = tid >> 6, lane = tid & 63;
  for (int r = w; r < 16; r += 3) {
    double vals[3], sum = 0.0, sq = 0.0;
    #pragma unroll
    for (int j = 0; j < 3; ++j) {
      const double v = sp[r][lane + (j << 6)];
      vals[j] = v; sum += v; sq += v * v;
    }
    #pragma unroll
    for (int m = 32; m >= 1; m >>= 1) {
      sum += __shfl_xor(sum, m); sq += __shfl_xor(sq, m);
    }
    const double mean = sum * (1.0 / 192.0);
    const double var = sq * (1.0 / 192.0) - mean * mean;
    const double den = sqrt(var + 1e-5) + 1e-5;
    #pragma unroll
    for (int j = 0; j < 3; ++j) {
      const int c = lane + (j << 6);
      const double vv = (double)gam[c] * ((vals[j] - mean) / den) + (double)bet[c];
      if (store64) ((double*)s1e)[(row0 + r) * 192 + c] = vv;
      else         ((float*)s1e)[(row0 + r) * 192 + c] = (float)vv;
    }
  }
}

// ---------------------------------------------------------------------------
// Phase 2 LDS map (dynamic, 144192 B) — same as R6
// ---------------------------------------------------------------------------
#define OFF_UH     0        /* 131072  f16 Uh chunk pages [32][256][8]      */
#define OFF_MASK   131072   /* 8192    int mask row                          */
#define OFF_HEP    139264   /* 512     f64 hep[64]                           */
#define OFF_ZEE    139776   /* 512     f64 ze[64]                            */
#define OFF_RHEP   140288   /* 512     f64 rhep[64]                          */
#define OFF_EPZRP  140800   /* 128     double2 epzrP[8]                      */
#define OFF_EPHHP  140928   /* 64      double2 ephhP[4]                      */
#define OFF_H2     140992   /* 512     f16 h packed h2[128]                  */
#define OFF_RH     141504   /* 512     f16 rh packed                         */
#define OFF_HF     142016   /* 1024    f32 h[256]                            */
#define OFF_Z      143040   /* 1024    f32 z[256]                            */
#define OFF_ZRP    144064   /* 64      float2 zrP[8]                         */
#define OFF_HHP    144128   /* 32      float2 hhP[4]                         */
#define OFF_FLAG   144160   /* 8       f32 flag[2]                           */
#define SCAN_LDS_BYTES 144192

__global__ __launch_bounds__(512, 2) void scan_kernel(
    const _Float16* __restrict__ uzr_g, const _Float16* __restrict__ uh_g,
    const float* __restrict__ U_EP, const _Float16* __restrict__ s1,
    const void* __restrict__ s1e_v, const int s1e64,
    const int* __restrict__ mask,
    const float* __restrict__ gam1, const float* __restrict__ bet1,
    const float* __restrict__ gamep1, const float* __restrict__ betep1,
    const float* __restrict__ W1, const float* __restrict__ b1,
    float* __restrict__ out)
{
  extern __shared__ char sm[];
  const int t = threadIdx.x;
  const int b = blockIdx.x;
  const int w = t >> 6;
  const int je  = t >> 2;            // EP-zr col 0..127
  const int qe  = t & 3;             // EP K-slice
  const int jeh = (t & 255) >> 2;    // EP-hh col 0..63

  float*  hf    = (float*)(sm + OFF_HF);
  float*  flagp = (float*)(sm + OFF_FLAG);
  double* hepd  = (double*)(sm + OFF_HEP);
  int*    maskl = (int*)(sm + OFF_MASK);

  // ---- stage Uh (linear copy; layout already chunk-major) ----
  {
    const v8h* src = (const v8h*)uh_g;
    v8h* dst = (v8h*)(sm + OFF_UH);
    #pragma unroll
    for (int i = 0; i < 16; ++i) dst[i * 512 + t] = src[i * 512 + t];
  }
  // ---- stage mask row ----
  #pragma unroll
  for (int i = 0; i < 4; ++i) maskl[i * 512 + t] = mask[((size_t)b << 11) + i * 512 + t];

  // ---- EP weights (f32 regs) ----
  float uez[16], ueh[16];
  #pragma unroll
  for (int i = 0; i < 16; ++i) uez[i] = U_EP[(size_t)(16 * qe + i) * 192 + je];
  #pragma unroll
  for (int i = 0; i < 16; ++i) ueh[i] = U_EP[(size_t)(16 * qe + i) * 192 + 128 + jeh];

  // ---- constants ----
  const float gz = gam1[t],                bz = bet1[t];
  const float gh = gam1[512 + (t & 255)],  bh = bet1[512 + (t & 255)];
  const float gse = gamep1[je],            bse = betep1[je];
  const float ghe = gamep1[128 + jeh],     bhe = betep1[128 + jeh];
  const double w1d = (double)W1[t & 63];
  const double b1d = (double)b1[0];
  const double* dptr = (const double*)s1e_v;
  const float*  fptr = (const float*)s1e_v;

  // ---- init state ----
  if (t < 128) { h2 z2; z2[0] = (_Float16)0.f; z2[1] = (_Float16)0.f;
                 ((h2*)(sm + OFF_H2))[t] = z2; }
  if (t < 256) hf[t] = 0.f;
  if (t < 64)  hepd[t] = 0.0;
  if (t < 2)   flagp[t] = 0.f;

  // ---- prefetch step 0 ----
  const size_t n0 = (size_t)b << 11;
  float  s1zr_c = (float)s1[n0 * 768 + t];
  float  s1h_c  = (float)s1[n0 * 768 + 512 + (t & 255)];
  double s1ezr_c = s1e64 ? dptr[n0 * 192 + je]
                         : (double)fptr[n0 * 192 + je];
  double s1ehh_c = s1e64 ? dptr[n0 * 192 + 128 + jeh]
                         : (double)fptr[n0 * 192 + 128 + jeh];
  __syncthreads();

  for (int tt = 0; tt < 2048; ++tt) {
    const size_t n = ((size_t)b << 11) | (size_t)tt;
    const float fz = (flagp[tt & 1] > 0.5f) ? 0.f : 1.f;

    // ---- Seg1: deferred h-write | prefetch t+1 | Uzr stream+dot | EP | is_end
    if (tt > 0 && t < 256) out[(n - 1) * 256 + t] = hf[t];

    // obscure base per-iteration so LICM cannot hoist the weight loads
    const v8h* uzb = (const v8h*)uzr_g;
    asm volatile("" : "+v"(uzb));

    // prologue: blocks 0,1 (chunks 0..7) in flight
    v8h wbuf[8];
    #pragma unroll
    for (int q = 0; q < 4; ++q) wbuf[q]     = uzb[(size_t)q * 512 + t];
    #pragma unroll
    for (int q = 0; q < 4; ++q) wbuf[4 + q] = uzb[(size_t)(4 + q) * 512 + t];

    // prefetch t+1 streaming data (stays in flight across barriers)
    const int ttn = (tt < 2047) ? tt + 1 : 2047;
    const size_t np1 = ((size_t)b << 11) | (size_t)ttn;
    const float  s1zr_n = (float)s1[np1 * 768 + t];
    const float  s1h_n  = (float)s1[np1 * 768 + 512 + (t & 255)];
    const double s1ezr_n = s1e64 ? dptr[np1 * 192 + je]
                                 : (double)fptr[np1 * 192 + je];
    const double s1ehh_n = s1e64 ? dptr[np1 * 192 + 128 + jeh]
                                 : (double)fptr[np1 * 192 + 128 + jeh];

    if (w == 7) {                       // is_end from hep (pre-update)
      double p = hepd[t & 63] * w1d;
      #pragma unroll
      for (int m = 1; m <= 32; m <<= 1) p += __shfl_xor(p, m);
      if (t == 448) {
        const float e = ((p + b1d) > 0.0) ? 1.f : 0.f;
        flagp[(tt + 1) & 1] = e;
        out[(size_t)33554432 + n] = e;
      }
    }

    // EP-zr dot first half (covers blk0/blk1 load latency)
    double de;
    const double2* hp = (const double2*)(hepd + 16 * qe);
    {
      double acc = 0.0;
      #pragma unroll
      for (int i = 0; i < 4; ++i) {
        const double2 hv2 = hp[i];
        acc += hv2.x * (double)uez[2 * i] + hv2.y * (double)uez[2 * i + 1];
      }
      de = acc;
    }

    // zr dot: pipelined blocks (chunks 4k..4k+3), accumulation order == R6
    const v8h* hv = (const v8h*)(sm + OFF_H2);
    float a0 = 0.f, a1 = 0.f, a2 = 0.f, a3 = 0.f;
    #pragma unroll
    for (int k = 0; k < 8; ++k) {
      #pragma unroll
      for (int i = 0; i < 4; ++i) {
        const v8h hc = hv[4 * k + i];
        const v8h wz = wbuf[(k & 1) * 4 + i];
        a0 = fdot2_(pr<0>(hc), pr<0>(wz), a0);
        a1 = fdot2_(pr<1>(hc), pr<1>(wz), a1);
        a2 = fdot2_(pr<2>(hc), pr<2>(wz), a2);
        a3 = fdot2_(pr<3>(hc), pr<3>(wz), a3);
      }
      if (k < 6) {
        #pragma unroll
        for (int q = 0; q < 4; ++q)
          wbuf[(k & 1) * 4 + q] = uzb[(size_t)(4 * (k + 2) + q) * 512 + t];
      }
      if (k == 3) {                     // EP-zr second half + reduce mid-stream
        double acc = de;
        #pragma unroll
        for (int i = 4; i < 8; ++i) {
          const double2 hv2 = hp[i];
          acc += hv2.x * (double)uez[2 * i] + hv2.y * (double)uez[2 * i + 1];
        }
        acc += __shfl_xor(acc, 1); acc += __shfl_xor(acc, 2);
        de = acc;
        double es = de, eq = de * de;
        #pragma unroll
        for (int m = 4; m <= 32; m <<= 1) { es += __shfl_xor(es, m); eq += __shfl_xor(eq, m); }
        if ((t & 63) == 0) ((double2*)(sm + OFF_EPZRP))[w] = make_double2(es, eq);
      }
    }
    const float d = ((a0 + a1) + (a2 + a3)) * fz;
    {
      float s_ = d, q_ = d * d;
      #pragma unroll
      for (int m = 1; m <= 32; m <<= 1) { s_ += __shfl_xor(s_, m); q_ += __shfl_xor(q_, m); }
      if ((t & 63) == 0) ((float2*)(sm + OFF_ZRP))[w] = make_float2(s_, q_);
    }
    wg_barrier();  // B1

    // ---- Seg2: LN512 -> z / rh | EP LN128 -> ze / rhep ----
    {
      float S = 0.f, Q = 0.f;
      const float4* zp = (const float4*)(sm + OFF_ZRP);
      #pragma unroll
      for (int i = 0; i < 4; ++i) { const float4 v = zp[i]; S += v.x + v.z; Q += v.y + v.w; }
      const float mean = S * (1.f / 512.f);
      const float var = Q * (1.f / 512.f) - mean * mean;
      const float inv = 1.f / (sqrtf(var + 1e-5f) + 1e-5f);
      const float s2v = gz * ((d - mean) * inv) + bz;
      float sv = 0.2f * (s1zr_c + s2v) + 0.5f;
      sv = fminf(fmaxf(sv, 0.f), 1.f);
      if (t < 256) ((float*)(sm + OFF_Z))[t] = sv;
      else {
        const float rhv = sv * (fz * hf[t - 256]);
        ((_Float16*)(sm + OFF_RH))[t - 256] = (_Float16)rhv;
      }
    }
    if ((t & 3) == 0) {                 // EP-zr finish (128 threads)
      double S = 0.0, Q = 0.0;
      const double2* ep = (const double2*)(sm + OFF_EPZRP);
      #pragma unroll
      for (int i = 0; i < 8; ++i) { S += ep[i].x; Q += ep[i].y; }
      const double mean = S * (1.0 / 128.0);
      const double var = Q * (1.0 / 128.0) - mean * mean;
      const double den = sqrt(var + 1e-5) + 1e-5;
      const double s2e = (double)gse * ((de - mean) / den) + (double)bse;
      double se = 0.2 * (s1ezr_c + s2e) + 0.5;
      se = fmin(fmax(se, 0.0), 1.0);
      if (je < 64) ((double*)(sm + OFF_ZEE))[je] = se;
      else         ((double*)(sm + OFF_RHEP))[je - 64] = se * hepd[je - 64];
    }
    wg_barrier();  // B2

    // ---- Seg3: hh dot (t<256, conflict-free pages) | EP-hh dot (t>=256) ----
    float dh = 0.f;
    double deh = 0.0;
    if (t < 256) {
      const v8h* rhv8 = (const v8h*)(sm + OFF_RH);
      const v8h* uhv  = (const v8h*)(sm + OFF_UH);
      float c0 = 0.f, c1 = 0.f, c2 = 0.f, c3 = 0.f;
      #pragma unroll
      for (int p = 0; p < 32; ++p) {
        const v8h rc = rhv8[p];
        const v8h uc = uhv[p * 256 + t];
        c0 = fdot2_(pr<0>(rc), pr<0>(uc), c0);
        c1 = fdot2_(pr<1>(rc), pr<1>(uc), c1);
        c2 = fdot2_(pr<2>(rc), pr<2>(uc), c2);
        c3 = fdot2_(pr<3>(rc), pr<3>(uc), c3);
      }
      dh = (c0 + c1) + (c2 + c3);
      float s_ = dh, q_ = dh * dh;
      #pragma unroll
      for (int m = 1; m <= 32; m <<= 1) { s_ += __shfl_xor(s_, m); q_ += __shfl_xor(q_, m); }
      if ((t & 63) == 0) ((float2*)(sm + OFF_HHP))[w] = make_float2(s_, q_);
    } else {
      const double2* rp = (const double2*)((double*)(sm + OFF_RHEP) + 16 * qe);
      double acc = 0.0;
      #pragma unroll
      for (int i = 0; i < 8; ++i) {
        const double2 rv = rp[i];
        acc += rv.x * (double)ueh[2 * i] + rv.y * (double)ueh[2 * i + 1];
      }
      acc += __shfl_xor(acc, 1); acc += __shfl_xor(acc, 2);
      deh = acc;
      double es = deh, eq = deh * deh;
      #pragma unroll
      for (int m = 4; m <= 32; m <<= 1) { es += __shfl_xor(es, m); eq += __shfl_xor(eq, m); }
      if ((t & 63) == 0) ((double2*)(sm + OFF_EPHHP))[w - 4] = make_double2(es, eq);
    }
    wg_barrier();  // B3

    // ---- Seg4: main h update | EP hep update ----
    const int xm = maskl[tt];
    if (t < 256) {
      float S = 0.f, Q = 0.f;
      const float4* hp4 = (const float4*)(sm + OFF_HHP);
      #pragma unroll
      for (int i = 0; i < 2; ++i) { const float4 v = hp4[i]; S += v.x + v.z; Q += v.y + v.w; }
      const float mean = S * (1.f / 256.f);
      const float var = Q * (1.f / 256.f) - mean * mean;
      const float inv = 1.f / (sqrtf(var + 1e-5f) + 1e-5f);
      const float hhv = gh * ((dh - mean) * inv) + bh;
      const float z = ((float*)(sm + OFF_Z))[t];
      const float hzf = fz * hf[t];
      const float hn = z * hzf + (1.f - z) * tanhf(s1h_c + hhv);
      const float hc_ = (xm > 0) ? hn : hzf;
      hf[t] = hc_;
      const float ho = __shfl_xor(hc_, 1);
      if (!(t & 1)) {
        h2 p2; p2[0] = (_Float16)hc_; p2[1] = (_Float16)ho;
        ((h2*)(sm + OFF_H2))[t >> 1] = p2;
      }
    } else if ((t & 3) == 0) {          // EP finish (64 threads, col jeh)
      double S = 0.0, Q = 0.0;
      const double2* ep = (const double2*)(sm + OFF_EPHHP);
      #pragma unroll
      for (int i = 0; i < 4; ++i) { S += ep[i].x; Q += ep[i].y; }
      const double mean = S * (1.0 / 64.0);
      const double var = Q * (1.0 / 64.0) - mean * mean;
      const double den = sqrt(var + 1e-5) + 1e-5;
      const double hhe = (double)ghe * ((deh - mean) / den) + (double)bhe;
      const double ze = ((double*)(sm + OFF_ZEE))[jeh];
      const double hold = hepd[jeh];
      const double hepn = ze * hold + (1.0 - ze) * tanh(s1ehh_c + hhe);
      hepd[jeh] = (xm > 0) ? hepn : hold;
    }
    wg_barrier();  // B4

    s1zr_c = s1zr_n; s1h_c = s1h_n; s1ezr_c = s1ezr_n; s1ehh_c = s1ehh_n;
  }
  // final h write (step 2047)
  if (t < 256) out[((((size_t)b << 11) | 2047)) * 256 + t] = hf[t];
}

// ---------------------------------------------------------------------------
extern "C" void kernel_launch(void* const* d_in, const int* in_sizes, int n_in,
                              void* d_out, int out_size, void* d_ws, size_t ws_size,
                              hipStream_t stream)
{
  (void)in_sizes; (void)n_in; (void)out_size;
  const float* x       = (const float*)d_in[0];
  const int*   mask    = (const int*)d_in[1];
  const float* W       = (const float*)d_in[2];
  const float* U       = (const float*)d_in[3];
  const float* bvec    = (const float*)d_in[4];
  const float* gammas  = (const float*)d_in[5];
  const float* betas   = (const float*)d_in[6];
  const float* W_EP    = (const float*)d_in[7];
  const float* U_EP    = (const float*)d_in[8];
  const float* b_EP    = (const float*)d_in[9];
  const float* gammasE = (const float*)d_in[10];
  const float* betasE  = (const float*)d_in[11];
  const float* W1_EP   = (const float*)d_in[12];
  const float* b1_EP   = (const float*)d_in[13];
  float* out = (float*)d_out;

  const size_t NR = 131072;                 // B*T
  const size_t S1_SZ    = NR * 768 * 2;     // f16
  const size_t S1E64_SZ = NR * 192 * 8;     // f64
  const size_t S1E32_SZ = NR * 192 * 4;     // f32 fallback
  const size_t WSMALL = 262144 + 131072 + 393216 + 196608;
  const int s1e64 = (ws_size >= S1_SZ + S1E64_SZ + WSMALL) ? 1 : 0;
  const size_t S1E_SZ = s1e64 ? S1E64_SZ : S1E32_SZ;
  if (ws_size < S1_SZ + S1E32_SZ + WSMALL) return;  // cannot run

  char* ws = (char*)d_ws;
  size_t off = 0;
  void* s1e      = (void*)(ws + off);      off += S1E_SZ;
  _Float16* s1   = (_Float16*)(ws + off);  off += S1_SZ;
  _Float16* uzr  = (_Float16*)(ws + off);  off += 262144;
  _Float16* uh   = (_Float16*)(ws + off);  off += 131072;
  _Float16* wt   = (_Float16*)(ws + off);  off += 393216;
  float* wept    = (float*)(ws + off);     off += 196608;

  prep_kernel<<<dim3(1728), dim3(256), 0, stream>>>(
      W, U, W_EP, wt, uzr, uh, wept);
  ph1_main_kernel<<<dim3(8192), dim3(256), 0, stream>>>(
      x, wt, bvec, gammas, betas, s1);
  ph1_ep_kernel<<<dim3(8192), dim3(192), 0, stream>>>(
      x, wept, b_EP, gammasE, betasE, s1e, s1e64);

  hipFuncSetAttribute(reinterpret_cast<const void*>(scan_kernel),
                      hipFuncAttributeMaxDynamicSharedMemorySize, SCAN_LDS_BYTES);
  scan_kernel<<<dim3(64), dim3(512), SCAN_LDS_BYTES, stream>>>(
      uzr, uh, U_EP, s1, (const void*)s1e, s1e64, mask,
      gammas + 768, betas + 768, gammasE + 192, betasE + 192,
      W1_EP, b1_EP, out);
}

// Round 13
// 18323.015 us; speedup vs baseline: 1.2816x; 1.0336x over previous
//
#include <hip/hip_runtime.h>

// ---------------------------------------------------------------------------
// R13 = R6 known-pass pipeline + TWO barrier-floor probes at 8192 steps.
// Probe readout: top-5 shows the larger probe; dur_us residual gives the other.
// ---------------------------------------------------------------------------

typedef _Float16 h2  __attribute__((ext_vector_type(2)));
typedef _Float16 v8h __attribute__((ext_vector_type(8)));

__device__ __forceinline__ float fdot2_(h2 a, h2 b, float c) {
#if __has_builtin(__builtin_amdgcn_fdot2)
  return __builtin_amdgcn_fdot2(a, b, c, false);
#else
  return c + (float)a[0] * (float)b[0] + (float)a[1] * (float)b[1];
#endif
}

template <int I>
__device__ __forceinline__ h2 pr(v8h v) {
  h2 r; r[0] = v[2 * I]; r[1] = v[2 * I + 1]; return r;
}

// Raw barrier: order LDS (lgkmcnt) but leave global loads/stores in flight.
__device__ __forceinline__ void wg_barrier() {
  __builtin_amdgcn_sched_barrier(0);
  asm volatile("s_waitcnt lgkmcnt(0)" ::: "memory");
  __builtin_amdgcn_sched_barrier(0);
  __builtin_amdgcn_s_barrier();
  __builtin_amdgcn_sched_barrier(0);
}

// ---------------------------------------------------------------------------
__global__ __launch_bounds__(256) void prep_kernel(
    const float* __restrict__ W, const float* __restrict__ U,
    const float* __restrict__ W_EP,
    _Float16* __restrict__ wt, _Float16* __restrict__ uzr,
    _Float16* __restrict__ uh, float* __restrict__ wept)
{
  const int blk = blockIdx.x;
  const int k = threadIdx.x;
  if (blk < 768) {
    const int j = blk;
    wt[(size_t)j * 256 + k] = (_Float16)W[(size_t)k * 768 + j];
  } else if (blk < 1280) {
    const int j = blk - 768;
    uzr[(size_t)j * 256 + k] = (_Float16)U[(size_t)k * 768 + j];
  } else if (blk < 1536) {
    const int j = blk - 1280;
    const int p = k >> 3, e = k & 7;
    uh[((size_t)p * 256 + j) * 8 + e] = (_Float16)U[(size_t)k * 768 + 512 + j];
  } else {
    const int j = blk - 1536;
    wept[(size_t)j * 256 + k] = W_EP[(size_t)k * 192 + j];
  }
}

// ---------------------------------------------------------------------------
__global__ __launch_bounds__(256) void ph1_main_kernel(
    const float* __restrict__ x, const _Float16* __restrict__ wt,
    const float* __restrict__ bvec, const float* __restrict__ gam,
    const float* __restrict__ bet, _Float16* __restrict__ s1out)
{
  __shared__ __align__(16) _Float16 xs[16][256];
  __shared__ float sp[16][768];
  const int tid = threadIdx.x;
  const size_t row0 = (size_t)blockIdx.x * 16;

  #pragma unroll
  for (int i = 0; i < 16; ++i)
    xs[i][tid] = (_Float16)x[(row0 + i) * 256 + tid];
  __syncthreads();

  #pragma unroll 1
  for (int cc = 0; cc < 3; ++cc) {
    const int col = cc * 256 + tid;
    const v8h* wp = (const v8h*)(wt + (size_t)col * 256);
    float acc[16];
    #pragma unroll
    for (int r = 0; r < 16; ++r) acc[r] = 0.f;
    #pragma unroll 4
    for (int c = 0; c < 32; ++c) {
      const v8h w8 = wp[c];
      #pragma unroll
      for (int r = 0; r < 16; ++r) {
        const v8h x8 = *(const v8h*)(&xs[r][c * 8]);
        acc[r] = fdot2_(pr<0>(x8), pr<0>(w8), acc[r]);
        acc[r] = fdot2_(pr<1>(x8), pr<1>(w8), acc[r]);
        acc[r] = fdot2_(pr<2>(x8), pr<2>(w8), acc[r]);
        acc[r] = fdot2_(pr<3>(x8), pr<3>(w8), acc[r]);
      }
    }
    const float bb = bvec[col];
    #pragma unroll
    for (int r = 0; r < 16; ++r) sp[r][col] = acc[r] + bb;
  }
  __syncthreads();

  const int w = tid >> 6, lane = tid & 63;
  for (int rr = 0; rr < 4; ++rr) {
    const int r = (w << 2) | rr;
    float vals[12], sum = 0.f, sq = 0.f;
    #pragma unroll
    for (int j = 0; j < 12; ++j) {
      const float v = sp[r][lane + (j << 6)];
      vals[j] = v; sum += v; sq += v * v;
    }
    #pragma unroll
    for (int m = 32; m >= 1; m >>= 1) {
      sum += __shfl_xor(sum, m); sq += __shfl_xor(sq, m);
    }
    const float mean = sum * (1.f / 768.f);
    const float var = sq * (1.f / 768.f) - mean * mean;
    const float inv = 1.f / (sqrtf(var + 1e-5f) + 1e-5f);
    #pragma unroll
    for (int j = 0; j < 12; ++j) {
      const int c = lane + (j << 6);
      s1out[(row0 + r) * 768 + c] =
          (_Float16)(gam[c] * ((vals[j] - mean) * inv) + bet[c]);
    }
  }
}

// ---------------------------------------------------------------------------
__global__ __launch_bounds__(192) void ph1_ep_kernel(
    const float* __restrict__ x, const float* __restrict__ wept,
    const float* __restrict__ bvec, const float* __restrict__ gam,
    const float* __restrict__ bet, void* __restrict__ s1e, const int store64)
{
  __shared__ __align__(16) float xs[16][256];
  __shared__ double sp[16][192];
  const int tid = threadIdx.x;
  const size_t row0 = (size_t)blockIdx.x * 16;

  for (int idx = tid; idx < 4096; idx += 192)
    xs[idx >> 8][idx & 255] = x[row0 * 256 + idx];
  __syncthreads();

  {
    const float4* wp = (const float4*)(wept + (size_t)tid * 256);
    double acc[16];
    #pragma unroll
    for (int r = 0; r < 16; ++r) acc[r] = 0.0;
    #pragma unroll 2
    for (int c = 0; c < 64; ++c) {
      const float4 w4 = wp[c];
      #pragma unroll
      for (int r = 0; r < 16; ++r) {
        const float4 x4 = *(const float4*)(&xs[r][c * 4]);
        acc[r] += (double)x4.x * (double)w4.x;
        acc[r] += (double)x4.y * (double)w4.y;
        acc[r] += (double)x4.z * (double)w4.z;
        acc[r] += (double)x4.w * (double)w4.w;
      }
    }
    const double bb = (double)bvec[tid];
    #pragma unroll
    for (int r = 0; r < 16; ++r) sp[r][tid] = acc[r] + bb;
  }
  __syncthreads();

  const int w = tid >> 6, lane = tid & 63;
  for (int r = w; r < 16; r += 3) {
    double vals[3], sum = 0.0, sq = 0.0;
    #pragma unroll
    for (int j = 0; j < 3; ++j) {
      const double v = sp[r][lane + (j << 6)];
      vals[j] = v; sum += v; sq += v * v;
    }
    #pragma unroll
    for (int m = 32; m >= 1; m >>= 1) {
      sum += __shfl_xor(sum, m); sq += __shfl_xor(sq, m);
    }
    const double mean = sum * (1.0 / 192.0);
    const double var = sq * (1.0 / 192.0) - mean * mean;
    const double den = sqrt(var + 1e-5) + 1e-5;
    #pragma unroll
    for (int j = 0; j < 3; ++j) {
      const int c = lane + (j << 6);
      const double vv = (double)gam[c] * ((vals[j] - mean) / den) + (double)bet[c];
      if (store64) ((double*)s1e)[(row0 + r) * 192 + c] = vv;
      else         ((float*)s1e)[(row0 + r) * 192 + c] = (float)vv;
    }
  }
}

// ---------------------------------------------------------------------------
#define OFF_UH     0
#define OFF_MASK   131072
#define OFF_HEP    139264
#define OFF_ZEE    139776
#define OFF_RHEP   140288
#define OFF_EPZRP  140800
#define OFF_EPHHP  140928
#define OFF_H2     140992
#define OFF_RH     141504
#define OFF_HF     142016
#define OFF_Z      143040
#define OFF_ZRP    144064
#define OFF_HHP    144128
#define OFF_FLAG   144160
#define SCAN_LDS_BYTES 144192

__global__ __launch_bounds__(512, 2) void scan_kernel(
    const _Float16* __restrict__ uzr_g, const _Float16* __restrict__ uh_g,
    const float* __restrict__ U_EP, const _Float16* __restrict__ s1,
    const void* __restrict__ s1e_v, const int s1e64,
    const int* __restrict__ mask,
    const float* __restrict__ gam1, const float* __restrict__ bet1,
    const float* __restrict__ gamep1, const float* __restrict__ betep1,
    const float* __restrict__ W1, const float* __restrict__ b1,
    float* __restrict__ out)
{
  extern __shared__ char sm[];
  const int t = threadIdx.x;
  const int b = blockIdx.x;
  const int w = t >> 6;
  const int je  = t >> 2;
  const int qe  = t & 3;
  const int jeh = (t & 255) >> 2;

  float*  hf    = (float*)(sm + OFF_HF);
  float*  flagp = (float*)(sm + OFF_FLAG);
  double* hepd  = (double*)(sm + OFF_HEP);
  int*    maskl = (int*)(sm + OFF_MASK);

  {
    const v8h* src = (const v8h*)uh_g;
    v8h* dst = (v8h*)(sm + OFF_UH);
    #pragma unroll
    for (int i = 0; i < 16; ++i) dst[i * 512 + t] = src[i * 512 + t];
  }
  #pragma unroll
  for (int i = 0; i < 4; ++i) maskl[i * 512 + t] = mask[((size_t)b << 11) + i * 512 + t];

  float uz[128];
  {
    const float4* up = (const float4*)uzr_g + (size_t)t * 32;
    #pragma unroll
    for (int c = 0; c < 32; ++c) {
      const float4 v = up[c];
      uz[4 * c + 0] = v.x; uz[4 * c + 1] = v.y;
      uz[4 * c + 2] = v.z; uz[4 * c + 3] = v.w;
    }
  }
  #pragma unroll
  for (int i = 0; i < 128; ++i) asm volatile("" : "+v"(uz[i]));

  float uez[16], ueh[16];
  #pragma unroll
  for (int i = 0; i < 16; ++i) uez[i] = U_EP[(size_t)(16 * qe + i) * 192 + je];
  #pragma unroll
  for (int i = 0; i < 16; ++i) ueh[i] = U_EP[(size_t)(16 * qe + i) * 192 + 128 + jeh];

  const float gz = gam1[t],                bz = bet1[t];
  const float gh = gam1[512 + (t & 255)],  bh = bet1[512 + (t & 255)];
  const float gse = gamep1[je],            bse = betep1[je];
  const float ghe = gamep1[128 + jeh],     bhe = betep1[128 + jeh];
  const double w1d = (double)W1[t & 63];
  const double b1d = (double)b1[0];
  const double* dptr = (const double*)s1e_v;
  const float*  fptr = (const float*)s1e_v;

  if (t < 128) { h2 z2; z2[0] = (_Float16)0.f; z2[1] = (_Float16)0.f;
                 ((h2*)(sm + OFF_H2))[t] = z2; }
  if (t < 256) hf[t] = 0.f;
  if (t < 64)  hepd[t] = 0.0;
  if (t < 2)   flagp[t] = 0.f;

  const size_t n0 = (size_t)b << 11;
  float  s1zr_c = (float)s1[n0 * 768 + t];
  float  s1h_c  = (float)s1[n0 * 768 + 512 + (t & 255)];
  double s1ezr_c = s1e64 ? dptr[n0 * 192 + je]
                         : (double)fptr[n0 * 192 + je];
  double s1ehh_c = s1e64 ? dptr[n0 * 192 + 128 + jeh]
                         : (double)fptr[n0 * 192 + 128 + jeh];
  __syncthreads();

  for (int tt = 0; tt < 2048; ++tt) {
    const size_t n = ((size_t)b << 11) | (size_t)tt;
    const float fz = (flagp[tt & 1] > 0.5f) ? 0.f : 1.f;

    if (tt > 0 && t < 256) out[(n - 1) * 256 + t] = hf[t];

    const int ttn = (tt < 2047) ? tt + 1 : 2047;
    const size_t np1 = ((size_t)b << 11) | (size_t)ttn;
    const float  s1zr_n = (float)s1[np1 * 768 + t];
    const float  s1h_n  = (float)s1[np1 * 768 + 512 + (t & 255)];
    const double s1ezr_n = s1e64 ? dptr[np1 * 192 + je]
                                 : (double)fptr[np1 * 192 + je];
    const double s1ehh_n = s1e64 ? dptr[np1 * 192 + 128 + jeh]
                                 : (double)fptr[np1 * 192 + 128 + jeh];

    if (w == 7) {
      double p = hepd[t & 63] * w1d;
      #pragma unroll
      for (int m = 1; m <= 32; m <<= 1) p += __shfl_xor(p, m);
      if (t == 448) {
        const float e = ((p + b1d) > 0.0) ? 1.f : 0.f;
        flagp[(tt + 1) & 1] = e;
        out[(size_t)33554432 + n] = e;
      }
    }

    float d;
    {
      const v8h* hv = (const v8h*)(sm + OFF_H2);
      float a0 = 0.f, a1 = 0.f, a2 = 0.f, a3 = 0.f;
      #pragma unroll
      for (int c = 0; c < 32; ++c) {
        const v8h hc = hv[c];
        a0 = fdot2_(pr<0>(hc), __builtin_bit_cast(h2, uz[4 * c + 0]), a0);
        a1 = fdot2_(pr<1>(hc), __builtin_bit_cast(h2, uz[4 * c + 1]), a1);
        a2 = fdot2_(pr<2>(hc), __builtin_bit_cast(h2, uz[4 * c + 2]), a2);
        a3 = fdot2_(pr<3>(hc), __builtin_bit_cast(h2, uz[4 * c + 3]), a3);
      }
      d = ((a0 + a1) + (a2 + a3)) * fz;
      float s_ = d, q_ = d * d;
      #pragma unroll
      for (int m = 1; m <= 32; m <<= 1) { s_ += __shfl_xor(s_, m); q_ += __shfl_xor(q_, m); }
      if ((t & 63) == 0) ((float2*)(sm + OFF_ZRP))[w] = make_float2(s_, q_);
    }
    double de;
    {
      const double2* hp = (const double2*)(hepd + 16 * qe);
      double acc = 0.0;
      #pragma unroll
      for (int i = 0; i < 8; ++i) {
        const double2 hv2 = hp[i];
        acc += hv2.x * (double)uez[2 * i] + hv2.y * (double)uez[2 * i + 1];
      }
      acc += __shfl_xor(acc, 1); acc += __shfl_xor(acc, 2);
      de = acc;
      double es = de, eq = de * de;
      #pragma unroll
      for (int m = 4; m <= 32; m <<= 1) { es += __shfl_xor(es, m); eq += __shfl_xor(eq, m); }
      if ((t & 63) == 0) ((double2*)(sm + OFF_EPZRP))[w] = make_double2(es, eq);
    }
    wg_barrier();  // B1

    {
      float S = 0.f, Q = 0.f;
      const float4* zp = (const float4*)(sm + OFF_ZRP);
      #pragma unroll
      for (int i = 0; i < 4; ++i) { const float4 v = zp[i]; S += v.x + v.z; Q += v.y + v.w; }
      const float mean = S * (1.f / 512.f);
      const float var = Q * (1.f / 512.f) - mean * mean;
      const float inv = 1.f / (sqrtf(var + 1e-5f) + 1e-5f);
      const float s2v = gz * ((d - mean) * inv) + bz;
      float sv = 0.2f * (s1zr_c + s2v) + 0.5f;
      sv = fminf(fmaxf(sv, 0.f), 1.f);
      if (t < 256) ((float*)(sm + OFF_Z))[t] = sv;
      else {
        const float rhv = sv * (fz * hf[t - 256]);
        ((_Float16*)(sm + OFF_RH))[t - 256] = (_Float16)rhv;
      }
    }
    if ((t & 3) == 0) {
      double S = 0.0, Q = 0.0;
      const double2* ep = (const double2*)(sm + OFF_EPZRP);
      #pragma unroll
      for (int i = 0; i < 8; ++i) { S += ep[i].x; Q += ep[i].y; }
      const double mean = S * (1.0 / 128.0);
      const double var = Q * (1.0 / 128.0) - mean * mean;
      const double den = sqrt(var + 1e-5) + 1e-5;
      const double s2e = (double)gse * ((de - mean) / den) + (double)bse;
      double se = 0.2 * (s1ezr_c + s2e) + 0.5;
      se = fmin(fmax(se, 0.0), 1.0);
      if (je < 64) ((double*)(sm + OFF_ZEE))[je] = se;
      else         ((double*)(sm + OFF_RHEP))[je - 64] = se * hepd[je - 64];
    }
    wg_barrier();  // B2

    float dh = 0.f;
    double deh = 0.0;
    if (t < 256) {
      const v8h* rhv8 = (const v8h*)(sm + OFF_RH);
      const v8h* uhv  = (const v8h*)(sm + OFF_UH);
      float c0 = 0.f, c1 = 0.f, c2 = 0.f, c3 = 0.f;
      #pragma unroll
      for (int p = 0; p < 32; ++p) {
        const v8h rc = rhv8[p];
        const v8h uc = uhv[p * 256 + t];
        c0 = fdot2_(pr<0>(rc), pr<0>(uc), c0);
        c1 = fdot2_(pr<1>(rc), pr<1>(uc), c1);
        c2 = fdot2_(pr<2>(rc), pr<2>(uc), c2);
        c3 = fdot2_(pr<3>(rc), pr<3>(uc), c3);
      }
      dh = (c0 + c1) + (c2 + c3);
      float s_ = dh, q_ = dh * dh;
      #pragma unroll
      for (int m = 1; m <= 32; m <<= 1) { s_ += __shfl_xor(s_, m); q_ += __shfl_xor(q_, m); }
      if ((t & 63) == 0) ((float2*)(sm + OFF_HHP))[w] = make_float2(s_, q_);
    } else {
      const double2* rp = (const double2*)((double*)(sm + OFF_RHEP) + 16 * qe);
      double acc = 0.0;
      #pragma unroll
      for (int i = 0; i < 8; ++i) {
        const double2 rv = rp[i];
        acc += rv.x * (double)ueh[2 * i] + rv.y * (double)ueh[2 * i + 1];
      }
      acc += __shfl_xor(acc, 1); acc += __shfl_xor(acc, 2);
      deh = acc;
      double es = deh, eq = deh * deh;
      #pragma unroll
      for (int m = 4; m <= 32; m <<= 1) { es += __shfl_xor(es, m); eq += __shfl_xor(eq, m); }
      if ((t & 63) == 0) ((double2*)(sm + OFF_EPHHP))[w - 4] = make_double2(es, eq);
    }
    wg_barrier();  // B3

    const int xm = maskl[tt];
    if (t < 256) {
      float S = 0.f, Q = 0.f;
      const float4* hp4 = (const float4*)(sm + OFF_HHP);
      #pragma unroll
      for (int i = 0; i < 2; ++i) { const float4 v = hp4[i]; S += v.x + v.z; Q += v.y + v.w; }
      const float mean = S * (1.f / 256.f);
      const float var = Q * (1.f / 256.f) - mean * mean;
      const float inv = 1.f / (sqrtf(var + 1e-5f) + 1e-5f);
      const float hhv = gh * ((dh - mean) * inv) + bh;
      const float z = ((float*)(sm + OFF_Z))[t];
      const float hzf = fz * hf[t];
      const float hn = z * hzf + (1.f - z) * tanhf(s1h_c + hhv);
      const float hc_ = (xm > 0) ? hn : hzf;
      hf[t] = hc_;
      const float ho = __shfl_xor(hc_, 1);
      if (!(t & 1)) {
        h2 p2; p2[0] = (_Float16)hc_; p2[1] = (_Float16)ho;
        ((h2*)(sm + OFF_H2))[t >> 1] = p2;
      }
    } else if ((t & 3) == 0) {
      double S = 0.0, Q = 0.0;
      const double2* ep = (const double2*)(sm + OFF_EPHHP);
      #pragma unroll
      for (int i = 0; i < 4; ++i) { S += ep[i].x; Q += ep[i].y; }
      const double mean = S * (1.0 / 64.0);
      const double var = Q * (1.0 / 64.0) - mean * mean;
      const double den = sqrt(var + 1e-5) + 1e-5;
      const double hhe = (double)ghe * ((deh - mean) / den) + (double)bhe;
      const double ze = ((double*)(sm + OFF_ZEE))[jeh];
      const double hold = hepd[jeh];
      const double hepn = ze * hold + (1.0 - ze) * tanh(s1ehh_c + hhe);
      hepd[jeh] = (xm > 0) ? hepn : hold;
    }
    wg_barrier();  // B4

    s1zr_c = s1zr_n; s1h_c = s1h_n; s1ezr_c = s1ezr_n; s1ehh_c = s1ehh_n;
  }
  if (t < 256) out[((((size_t)b << 11) | 2047)) * 256 + t] = hf[t];
}

// ===========================================================================
// Barrier-floor probes: 64 WGs x 512 thr, 144KB LDS (same occupancy), 8192
// steps x 4 barriers. Only a flag read + fz accumulate between barriers.
// ===========================================================================
__global__ __launch_bounds__(512, 2) void bar_probe_raw(float* __restrict__ sink)
{
  extern __shared__ char sm[];
  float* flagp = (float*)(sm + OFF_FLAG);
  const int t = threadIdx.x;
  if (t < 2) flagp[t] = 0.f;
  __syncthreads();
  float acc = 0.f;
  #pragma unroll 1
  for (int tt = 0; tt < 8192; ++tt) {
    const float fz = (flagp[tt & 1] > 0.5f) ? 0.f : 1.f;
    acc += fz;
    wg_barrier(); wg_barrier(); wg_barrier(); wg_barrier();
  }
  if (acc > 1e30f) sink[t] = acc;
}

__global__ __launch_bounds__(512, 2) void bar_probe_sync(float* __restrict__ sink)
{
  extern __shared__ char sm[];
  float* flagp = (float*)(sm + OFF_FLAG);
  const int t = threadIdx.x;
  if (t < 2) flagp[t] = 0.f;
  __syncthreads();
  float acc = 0.f;
  #pragma unroll 1
  for (int tt = 0; tt < 8192; ++tt) {
    const float fz = (flagp[tt & 1] > 0.5f) ? 0.f : 1.f;
    acc += fz;
    __syncthreads(); __syncthreads(); __syncthreads(); __syncthreads();
  }
  if (acc > 1e30f) sink[t] = acc;
}

// ---------------------------------------------------------------------------
extern "C" void kernel_launch(void* const* d_in, const int* in_sizes, int n_in,
                              void* d_out, int out_size, void* d_ws, size_t ws_size,
                              hipStream_t stream)
{
  (void)in_sizes; (void)n_in; (void)out_size;
  const float* x       = (const float*)d_in[0];
  const int*   mask    = (const int*)d_in[1];
  const float* W       = (const float*)d_in[2];
  const float* U       = (const float*)d_in[3];
  const float* bvec    = (const float*)d_in[4];
  const float* gammas  = (const float*)d_in[5];
  const float* betas   = (const float*)d_in[6];
  const float* W_EP    = (const float*)d_in[7];
  const float* U_EP    = (const float*)d_in[8];
  const float* b_EP    = (const float*)d_in[9];
  const float* gammasE = (const float*)d_in[10];
  const float* betasE  = (const float*)d_in[11];
  const float* W1_EP   = (const float*)d_in[12];
  const float* b1_EP   = (const float*)d_in[13];
  float* out = (float*)d_out;

  const size_t NR = 131072;
  const size_t S1_SZ    = NR * 768 * 2;
  const size_t S1E64_SZ = NR * 192 * 8;
  const size_t S1E32_SZ = NR * 192 * 4;
  const size_t WSMALL = 262144 + 131072 + 393216 + 196608;
  const int s1e64 = (ws_size >= S1_SZ + S1E64_SZ + WSMALL) ? 1 : 0;
  const size_t S1E_SZ = s1e64 ? S1E64_SZ : S1E32_SZ;
  if (ws_size < S1_SZ + S1E32_SZ + WSMALL) return;

  char* ws = (char*)d_ws;
  size_t off = 0;
  void* s1e      = (void*)(ws + off);      off += S1E_SZ;
  _Float16* s1   = (_Float16*)(ws + off);  off += S1_SZ;
  _Float16* uzr  = (_Float16*)(ws + off);  off += 262144;
  _Float16* uh   = (_Float16*)(ws + off);  off += 131072;
  _Float16* wt   = (_Float16*)(ws + off);  off += 393216;
  float* wept    = (float*)(ws + off);     off += 196608;

  prep_kernel<<<dim3(1728), dim3(256), 0, stream>>>(
      W, U, W_EP, wt, uzr, uh, wept);
  ph1_main_kernel<<<dim3(8192), dim3(256), 0, stream>>>(
      x, wt, bvec, gammas, betas, s1);
  ph1_ep_kernel<<<dim3(8192), dim3(192), 0, stream>>>(
      x, wept, b_EP, gammasE, betasE, s1e, s1e64);

  hipFuncSetAttribute(reinterpret_cast<const void*>(scan_kernel),
                      hipFuncAttributeMaxDynamicSharedMemorySize, SCAN_LDS_BYTES);
  scan_kernel<<<dim3(64), dim3(512), SCAN_LDS_BYTES, stream>>>(
      uzr, uh, U_EP, s1, (const void*)s1e, s1e64, mask,
      gammas + 768, betas + 768, gammasE + 192, betasE + 192,
      W1_EP, b1_EP, out);

  float* sink = (float*)wt;   // consumed by ph1_main already; safe scratch

  hipFuncSetAttribute(reinterpret_cast<const void*>(bar_probe_raw),
                      hipFuncAttributeMaxDynamicSharedMemorySize, SCAN_LDS_BYTES);
  bar_probe_raw<<<dim3(64), dim3(512), SCAN_LDS_BYTES, stream>>>(sink);

  hipFuncSetAttribute(reinterpret_cast<const void*>(bar_probe_sync),
                      hipFuncAttributeMaxDynamicSharedMemorySize, SCAN_LDS_BYTES);
  bar_probe_sync<<<dim3(64), dim3(512), SCAN_LDS_BYTES, stream>>>(sink);
}